// Round 11
// baseline (568.435 us; speedup 1.0000x reference)
//
#include <hip/hip_runtime.h>
#include <stdint.h>

typedef unsigned short u16;
typedef unsigned int u32;
typedef __attribute__((ext_vector_type(8))) short s8v;   // 8 bf16 = 4 VGPR (MFMA A/B frag)
typedef __attribute__((ext_vector_type(4))) float f4v;   // MFMA C/D frag
typedef __attribute__((ext_vector_type(8))) u16 u16x8;

// ---------- bf16 helpers ----------
__device__ __forceinline__ float bf2f(u16 u){
  union { u32 i; float f; } v; v.i = ((u32)u) << 16; return v.f;
}
__device__ __forceinline__ u16 f2bf(float f){
  union { float f; u32 i; } v; v.f = f;
  u32 i = v.i;
  return (u16)((i + 0x7fffu + ((i >> 16) & 1u)) >> 16); // RNE
}
__device__ __forceinline__ float sgnf(float w){
  return (w > 0.f) ? 1.f : ((w < 0.f) ? -1.f : 0.f);
}
__device__ __forceinline__ u16 sgn_bf(float w){
  return (w > 0.f) ? (u16)0x3F80 : ((w < 0.f) ? (u16)0xBF80 : (u16)0);
}

// ---------- generate all quantized weight forms + fused absum partials ----------
// Each weight element is read EXACTLY ONCE across the grid, and all region boundaries
// (2097152 / +73728 / +2048 / +2560) are multiples of 64 -> every wave has a uniform
// slot: shfl-reduce |w| and do ONE atomic per wave into 256-way partials (no extra pass).
__global__ __launch_bounds__(256) void k_signgen(const float* __restrict__ w1, const float* __restrict__ w2,
                                                 const float* __restrict__ wfc1, const float* __restrict__ wfc2,
                                                 u16* __restrict__ qw1b, u16* __restrict__ qw2b,
                                                 u16* __restrict__ qfc1b, float* __restrict__ qwfc2,
                                                 float* __restrict__ partials){
  int i = blockIdx.x * 256 + threadIdx.x;
  float av = 0.f; int slot;
  if (i < 2097152){
    int j = i & 7, lane = (i >> 3) & 63, fid = i >> 9;
    int kstep = fid >> 4, nt = fid & 15;
    int co = nt*16 + (lane & 15);
    int k_phys = kstep*32 + (lane >> 4)*8 + j;
    int px = k_phys >> 7, c = k_phys & 127;
    float wv = wfc1[(size_t)co*8192 + c*64 + px];
    qfc1b[i] = sgn_bf(wv);
    av = fabsf(wv); slot = 2;
  } else if (i < 2097152 + 73728){
    int i2 = i - 2097152;
    int j = i2 & 7, lane = (i2 >> 3) & 63, fid = i2 >> 9;  // 0..143
    int s = fid >> 4, ks = (fid >> 3) & 1, nt = fid & 7;
    int co = (lane & 15)*8 + nt;
    int c = ks*32 + (lane >> 4)*8 + j;
    float wv = w2[((size_t)co*64 + c)*9 + s];
    qw2b[i2] = sgn_bf(wv);
    av = fabsf(wv); slot = 1;
  } else if (i < 2097152 + 73728 + 2048){
    int i3 = i - (2097152 + 73728);
    int j = i3 & 7, lane = (i3 >> 3) & 63, nt = i3 >> 9;   // 0..3
    int co = nt*16 + (lane & 15);
    int k = (lane >> 4)*8 + j;
    if (k < 27){
      float wv = w1[co*27 + k];
      qw1b[i3] = sgn_bf(wv);
      av = fabsf(wv);
    } else qw1b[i3] = (u16)0;
    slot = 0;
  } else {
    int i4 = i - (2097152 + 73728 + 2048);
    float wv = wfc2[i4];
    qwfc2[i4] = sgnf(wv);
    av = fabsf(wv); slot = 3;
  }
  #pragma unroll
  for (int off = 32; off > 0; off >>= 1) av += __shfl_xor(av, off);
  if ((threadIdx.x & 63) == 0) atomicAdd(partials + slot*256 + (blockIdx.x & 255), av);
}

// ---------- reduce 4x256 partials -> absum[4] ----------
__global__ void k_red4(const float* __restrict__ partials, float* __restrict__ absum){
  int t = threadIdx.x, w = t >> 6, lane = t & 63;
  const float* p = partials + w*256;
  float s = p[lane] + p[lane + 64] + p[lane + 128] + p[lane + 192];
  #pragma unroll
  for (int off = 32; off > 0; off >>= 1) s += __shfl_xor(s, off);
  if (lane == 0) absum[w] = s;
}

// ---------- conv1 via MFMA: im2col in LDS + fused BN1 stats + in-lane 2x2 pool ----------
__global__ __launch_bounds__(256) void k_conv1m(const float* __restrict__ x, const u16* __restrict__ qw1b,
                                                const float* __restrict__ absum, u16* __restrict__ p1raw,
                                                float* __restrict__ gs, float* __restrict__ gq){
  __shared__ float xs[3*34*36];              // fp32 halo image, data y=1..32, x=2..33
  __shared__ __align__(16) u16 acol[256*40]; // im2col chunk: 256 rows x 40 u16 (32 used)
  __shared__ float ls1[64], ls2[64];
  int n = blockIdx.x, t = threadIdx.x;
  if (t < 64){ ls1[t] = 0.f; ls2[t] = 0.f; }
  for (int i = t; i < 3672; i += 256) xs[i] = 0.f;
  __syncthreads();
  const float4* xg = (const float4*)(x + (size_t)n * 3072);
  for (int i = t; i < 768; i += 256){
    float4 v = xg[i];
    int ci = i >> 8, rem = i & 255, y = rem >> 3, xq = (rem & 7) * 4;
    int base = ci*1224 + (y+1)*36 + 2 + xq;
    xs[base+0] = v.x; xs[base+1] = v.y; xs[base+2] = v.z; xs[base+3] = v.w;
  }
  int w = t >> 6, lane = t & 63, l15 = lane & 15, q = lane >> 4;
  const s8v* bp = (const s8v*)qw1b;
  s8v bf[4];
  #pragma unroll
  for (int nt = 0; nt < 4; ++nt) bf[nt] = bp[nt*64 + lane];
  float alpha = absum[0] * (1.f/1728.f);
  u16* p1img = p1raw + (size_t)n * 16384;
  float s1v[4], s2v[4];
  #pragma unroll
  for (int nt = 0; nt < 4; ++nt){ s1v[nt] = 0.f; s2v[nt] = 0.f; }
  for (int chunk = 0; chunk < 4; ++chunk){
    __syncthreads();
    {
      int mg = chunk*256 + t;
      int g = mg >> 2, s = mg & 3;
      int iy = 2*(g >> 4) + (s >> 1), ix = 2*(g & 15) + (s & 1);
      const float* xb = xs + iy*36 + ix + 1;
      u32 pk2[16];
      #pragma unroll
      for (int kk = 0; kk < 16; ++kk){
        int k0 = 2*kk, k1 = 2*kk + 1;
        u32 lo = (k0 < 27) ? (u32)f2bf(xb[(k0/9)*1224 + ((k0%9)/3)*36 + (k0%3)]) : 0u;
        u32 hi = (k1 < 27) ? (u32)f2bf(xb[(k1/9)*1224 + ((k1%9)/3)*36 + (k1%3)]) : 0u;
        pk2[kk] = lo | (hi << 16);
      }
      u32* ar = (u32*)(acol + t*40);
      #pragma unroll
      for (int v = 0; v < 4; ++v)
        *(uint4*)(ar + v*4) = make_uint4(pk2[v*4], pk2[v*4+1], pk2[v*4+2], pk2[v*4+3]);
    }
    __syncthreads();
    #pragma unroll
    for (int i = 0; i < 4; ++i){
      int tl = w*4 + i;
      s8v av = *(const s8v*)(acol + (tl*16 + l15)*40 + q*8);
      int g = chunk*64 + tl*4 + q;
      u16* drow = p1img + g*64 + l15;
      #pragma unroll
      for (int nt = 0; nt < 4; ++nt){
        f4v c = (f4v)(0.0f);
        c = __builtin_amdgcn_mfma_f32_16x16x32_bf16(av, bf[nt], c, 0, 0, 0);
        s1v[nt] += c[0] + c[1] + c[2] + c[3];
        s2v[nt] += c[0]*c[0] + c[1]*c[1] + c[2]*c[2] + c[3]*c[3];
        float pm = fmaxf(fmaxf(c[0], c[1]), fmaxf(c[2], c[3]));
        drow[nt*16] = f2bf(pm * alpha);
      }
    }
  }
  #pragma unroll
  for (int nt = 0; nt < 4; ++nt){
    s1v[nt] += __shfl_xor(s1v[nt], 16); s1v[nt] += __shfl_xor(s1v[nt], 32);
    s2v[nt] += __shfl_xor(s2v[nt], 16); s2v[nt] += __shfl_xor(s2v[nt], 32);
  }
  if (q == 0){
    #pragma unroll
    for (int nt = 0; nt < 4; ++nt){
      atomicAdd(&ls1[nt*16 + l15], s1v[nt]);
      atomicAdd(&ls2[nt*16 + l15], s2v[nt]);
    }
  }
  __syncthreads();
  if (t < 64){
    atomicAdd(gs + t, ls1[t] * alpha);
    atomicAdd(gq + t, ls2[t] * alpha * alpha);
  }
}

// ---------- conv2 via MFMA, nt-SPLIT waves (R10 post-mortem: old version was L1-bound
// on redundant B loads -- every wave streamed the full 144 KB sign table; 9.4 MB/CU
// through L1 ~= the entire 151k-cyc wall). Wave w now owns co pair {2w, 2w+1} and ALL
// 16 rows: per (s,ks) only 2 B loads + 16 ds_read_b128 + 32 MFMA; B traffic/wave 4x down.
// BN1 inline staging; in-register 2x2 pool; BN2 stats direct to global atomics. ----------
__global__ __launch_bounds__(256, 2) void k_conv2m(const u16* __restrict__ p1raw, const u16* __restrict__ qw2b,
                                                   const float* __restrict__ absum,
                                                   const float* __restrict__ s1, const float* __restrict__ q1,
                                                   const float* __restrict__ g1, const float* __restrict__ b1,
                                                   u16* __restrict__ p2raw,
                                                   float* __restrict__ gs, float* __restrict__ gq){
  __shared__ __align__(16) u16 img[16384];   // 32 KB exactly (5 blocks/CU capacity)
  int n = blockIdx.x, t = threadIdx.x;
  int c0 = (t & 7) * 8;
  float scv[8], biv[8];
  #pragma unroll
  for (int j = 0; j < 8; ++j){
    float m = s1[c0+j] * (1.f/1048576.f);
    float var = q1[c0+j] * (1.f/1048576.f) - m*m;
    float sc = g1[c0+j] * rsqrtf(var + 1e-5f);
    scv[j] = sc; biv[j] = b1[c0+j] - m*sc;
  }
  const u16* src = p1raw + (size_t)n * 16384;
  #pragma unroll
  for (int i = 0; i < 8; ++i){
    int id = i*256 + t;            // = px*8 + unit, unit == t&7
    int px = id >> 3, unit = id & 7;
    int su = unit ^ (px & 7);
    u16x8 v = *(const u16x8*)(src + id*8);
    u16x8 o;
    #pragma unroll
    for (int j = 0; j < 8; ++j)
      o[j] = f2bf(fmaxf(bf2f(v[j]) * scv[j] + biv[j], 0.f));
    *(u16x8*)(img + px*64 + su*8) = o;
  }
  __syncthreads();
  int w = t >> 6, lane = t & 63, l15 = lane & 15, q = lane >> 4;
  const s8v* bp = (const s8v*)qw2b;
  f4v acc[16][2];
  #pragma unroll
  for (int a = 0; a < 16; ++a){ acc[a][0] = (f4v)(0.0f); acc[a][1] = (f4v)(0.0f); }
  #pragma unroll
  for (int dy = 0; dy < 3; ++dy){
    #pragma unroll
    for (int dx = 0; dx < 3; ++dx){
      int s = dy*3 + dx;
      int xv = l15 + dx - 1;
      bool vx = (xv >= 0) && (xv < 16);
      int xc = min(max(xv, 0), 15);
      #pragma unroll
      for (int ks = 0; ks < 2; ++ks){
        s8v bf0 = bp[((s*2 + ks)*8 + 2*w)*64 + lane];
        s8v bf1 = bp[((s*2 + ks)*8 + 2*w + 1)*64 + lane];
        #pragma unroll
        for (int mt = 0; mt < 16; ++mt){
          int yv = mt + dy - 1;
          if (yv < 0 || yv > 15) continue;
          int px = yv*16 + xc;
          int su = (ks*4 + q) ^ (px & 7);
          s8v av = *(const s8v*)(img + px*64 + su*8);
          if (!vx) av = (s8v)(short)0;
          acc[mt][0] = __builtin_amdgcn_mfma_f32_16x16x32_bf16(av, bf0, acc[mt][0], 0, 0, 0);
          acc[mt][1] = __builtin_amdgcn_mfma_f32_16x16x32_bf16(av, bf1, acc[mt][1], 0, 0, 0);
        }
      }
    }
  }
  float alpha = absum[1] * (1.f/73728.f);
  float sa0 = 0.f, sa1 = 0.f, sq0 = 0.f, sq1 = 0.f;
  #pragma unroll
  for (int mp = 0; mp < 8; ++mp){           // pooled row (from rows 2mp, 2mp+1)
    #pragma unroll
    for (int rp = 0; rp < 2; ++rp){         // pooled col (from lane cols 2rp, 2rp+1)
      float v0 = acc[2*mp][0][2*rp]     * alpha;
      float v1 = acc[2*mp][0][2*rp+1]   * alpha;
      float v2 = acc[2*mp+1][0][2*rp]   * alpha;
      float v3 = acc[2*mp+1][0][2*rp+1] * alpha;
      sa0 += v0 + v1 + v2 + v3;
      sq0 += v0*v0 + v1*v1 + v2*v2 + v3*v3;
      u32 pk = (u32)f2bf(fmaxf(fmaxf(v0, v1), fmaxf(v2, v3)));
      float u0 = acc[2*mp][1][2*rp]     * alpha;
      float u1 = acc[2*mp][1][2*rp+1]   * alpha;
      float u2 = acc[2*mp+1][1][2*rp]   * alpha;
      float u3 = acc[2*mp+1][1][2*rp+1] * alpha;
      sa1 += u0 + u1 + u2 + u3;
      sq1 += u0*u0 + u1*u1 + u2*u2 + u3*u3;
      pk |= ((u32)f2bf(fmaxf(fmaxf(u0, u1), fmaxf(u2, u3)))) << 16;
      int opx = mp*8 + q*2 + rp;            // pooled 8x8 index
      *(u32*)(p2raw + ((size_t)n*64 + opx)*128 + l15*8 + 2*w) = pk;
    }
  }
  sa0 += __shfl_xor(sa0, 16); sa0 += __shfl_xor(sa0, 32);
  sa1 += __shfl_xor(sa1, 16); sa1 += __shfl_xor(sa1, 32);
  sq0 += __shfl_xor(sq0, 16); sq0 += __shfl_xor(sq0, 32);
  sq1 += __shfl_xor(sq1, 16); sq1 += __shfl_xor(sq1, 32);
  if (q == 0){
    int co = l15*8 + 2*w;
    atomicAdd(gs + co, sa0);     atomicAdd(gq + co, sq0);
    atomicAdd(gs + co + 1, sa1); atomicAdd(gq + co + 1, sq1);
  }
}

// ---------- BN2 affine + ReLU in-place on p2[1024][64px][128c] (params inline) ----------
__global__ __launch_bounds__(256) void k_bn2(u16* __restrict__ p2,
                                             const float* __restrict__ s2, const float* __restrict__ q2,
                                             const float* __restrict__ g2, const float* __restrict__ b2){
  size_t i = (size_t)blockIdx.x * 256 + threadIdx.x;   // unit of 8 u16
  int c0 = ((int)(i & 15)) * 8;
  float scv[8], biv[8];
  #pragma unroll
  for (int j = 0; j < 8; ++j){
    float m = s2[c0+j] * (1.f/262144.f);
    float var = q2[c0+j] * (1.f/262144.f) - m*m;
    float sc = g2[c0+j] * rsqrtf(var + 1e-5f);
    scv[j] = sc; biv[j] = b2[c0+j] - m*sc;
  }
  u16x8 v = *(u16x8*)(p2 + i*8);
  u16x8 o;
  #pragma unroll
  for (int j = 0; j < 8; ++j)
    o[j] = f2bf(fmaxf(bf2f(v[j]) * scv[j] + biv[j], 0.f));
  *(u16x8*)(p2 + i*8) = o;
}

// ---------- fc1 via MFMA, k-split 16: p2[1024][8192] x signs -> h3p[16][1024][256] ----------
__global__ __launch_bounds__(256) void k_fc1m(const u16* __restrict__ p2, const u16* __restrict__ qfc1b,
                                              const float* __restrict__ absum, float* __restrict__ h3p){
  int t = threadIdx.x;
  int bm = blockIdx.x, bn = blockIdx.y, kb = blockIdx.z;
  int w = t >> 6, lane = t & 63, l15 = lane & 15, q = lane >> 4;
  int rowbase = bm*128 + (w >> 1)*64;
  int ntb = bn*8 + (w & 1)*4;
  const s8v* bp = (const s8v*)qfc1b;
  f4v acc[4][4];
  #pragma unroll
  for (int a = 0; a < 4; ++a)
    #pragma unroll
    for (int b = 0; b < 4; ++b) acc[a][b] = (f4v)(0.0f);
  #pragma unroll 2
  for (int ks = 0; ks < 16; ++ks){
    int kst = kb*16 + ks;
    s8v bf[4], af[4];
    #pragma unroll
    for (int nt = 0; nt < 4; ++nt) bf[nt] = bp[(kst*16 + ntb + nt)*64 + lane];
    #pragma unroll
    for (int mt = 0; mt < 4; ++mt)
      af[mt] = *(const s8v*)(p2 + (size_t)(rowbase + mt*16 + l15)*8192 + kst*32 + q*8);
    #pragma unroll
    for (int mt = 0; mt < 4; ++mt)
      #pragma unroll
      for (int nt = 0; nt < 4; ++nt)
        acc[mt][nt] = __builtin_amdgcn_mfma_f32_16x16x32_bf16(af[mt], bf[nt], acc[mt][nt], 0, 0, 0);
  }
  float alpha = absum[2] * (1.f/2097152.f);
  float* dst = h3p + (size_t)kb * 262144;
  #pragma unroll
  for (int mt = 0; mt < 4; ++mt)
    #pragma unroll
    for (int nt = 0; nt < 4; ++nt){
      int col = (ntb + nt)*16 + l15;
      #pragma unroll
      for (int r = 0; r < 4; ++r)
        dst[(size_t)(rowbase + mt*16 + q*4 + r)*256 + col] = acc[mt][nt][r] * alpha;
    }
}

// ---------- reduce k-split slabs + BN3 stats + materialize h3 ----------
__global__ __launch_bounds__(256) void k_fin3f(const float* __restrict__ h3p, float* __restrict__ h3,
                                               float* __restrict__ s3, float* __restrict__ q3){
  int jb = blockIdx.x, ns = blockIdx.y, t = threadIdx.x;
  int jj = t & 31, nn = t >> 5;
  int j = jb*32 + jj;
  float s1 = 0.f, s2 = 0.f;
  for (int i = nn; i < 128; i += 8){
    int n = i*8 + ns;
    float v = 0.f;
    #pragma unroll 8
    for (int kb = 0; kb < 16; ++kb) v += h3p[(size_t)kb*262144 + n*256 + j];
    h3[n*256 + j] = v;
    s1 += v; s2 += v*v;
  }
  __shared__ float l1[256], l2[256];
  l1[t] = s1; l2[t] = s2;
  __syncthreads();
  if (t < 32){
    float a = 0.f, b = 0.f;
    #pragma unroll
    for (int k = 0; k < 8; ++k){ a += l1[t+32*k]; b += l2[t+32*k]; }
    atomicAdd(s3 + jb*32 + t, a); atomicAdd(q3 + jb*32 + t, b);
  }
}

// ---------- fc2: relu(bn3(h3)) @ sign(wfc2)^T -> out[1024,10] fp32 (BN3 params inline) ----------
__global__ __launch_bounds__(64) void k_fc2(const float* __restrict__ h3, const float* __restrict__ qwfc2,
                                            const float* __restrict__ absum,
                                            const float* __restrict__ s3, const float* __restrict__ q3,
                                            const float* __restrict__ g3, const float* __restrict__ b3,
                                            float* __restrict__ out){
  int n = blockIdx.x, lane = threadIdx.x;
  float a[4];
  #pragma unroll
  for (int i = 0; i < 4; ++i){
    int j = lane + 64*i;
    float m = s3[j] * (1.f/1024.f);
    float var = q3[j] * (1.f/1024.f) - m*m;
    float sc = g3[j] * rsqrtf(var + 1e-5f);
    float v = h3[(size_t)n*256 + j] * sc + (b3[j] - m*sc);
    a[i] = fmaxf(v, 0.f);
  }
  float alpha = absum[3] * (1.f/2560.f);
  #pragma unroll
  for (int k = 0; k < 10; ++k){
    float p = 0.f;
    #pragma unroll
    for (int i = 0; i < 4; ++i) p += a[i] * qwfc2[k*256 + lane + 64*i];
    #pragma unroll
    for (int off = 32; off > 0; off >>= 1) p += __shfl_down(p, off);
    if (lane == 0) out[n*10 + k] = p * alpha;
  }
}

extern "C" void kernel_launch(void* const* d_in, const int* in_sizes, int n_in,
                              void* d_out, int out_size, void* d_ws, size_t ws_size,
                              hipStream_t stream){
  (void)in_sizes; (void)n_in; (void)out_size; (void)ws_size;
  const float* x    = (const float*)d_in[0];
  const float* w1   = (const float*)d_in[1];
  const float* g1   = (const float*)d_in[2];
  const float* b1   = (const float*)d_in[3];
  const float* w2   = (const float*)d_in[4];
  const float* g2   = (const float*)d_in[5];
  const float* b2   = (const float*)d_in[6];
  const float* wfc1 = (const float*)d_in[7];
  const float* g3   = (const float*)d_in[8];
  const float* b3   = (const float*)d_in[9];
  const float* wfc2 = (const float*)d_in[10];
  float* out = (float*)d_out;

  float* wsf = (float*)d_ws;
  char*  wsb = (char*)d_ws;
  float* absum = wsf;
  float* s1 = wsf + 16;   float* q1 = wsf + 80;
  float* s2 = wsf + 144;  float* q2 = wsf + 272;
  float* s3 = wsf + 1024; float* q3 = wsf + 1280;
  float* partials = wsf + 2048;                      // 4x256 fp32 (zeroed)
  u16*   qw1b  = (u16*)(wsf + 4096);                 // 2048 u16 conv1 B-frags
  u16*   qw2b  = (u16*)(wsb + (64u << 10));          // 144 KB bf16 B-frags
  float* qwfc2 = (float*)(wsb + (256u << 10));       // 10 KB fp32
  float* h3    = (float*)(wsb + (1ull << 20));       // 1 MB fp32 [1024][256]
  u16*   qfc1b = (u16*)(wsb + (2ull << 20));         // 4 MB bf16 B-frags
  u16*   p1t   = (u16*)(wsb + (8ull << 20) + 4096);  // 32 MB bf16 [1024][256][64]
  u16*   p2    = (u16*)(wsb + (112ull << 20));       // 16 MB bf16 [1024][64][128] pooled raw -> bn2 in place
  float* h3p   = (float*)(wsb + (128ull << 20));     // 16 MB fp32 [16][1024][256]

  hipMemsetAsync(wsf, 0, 3072 * sizeof(float), stream);
  k_signgen<<<8498, 256, 0, stream>>>(w1, w2, wfc1, wfc2, qw1b, qw2b, qfc1b, qwfc2, partials);
  k_red4<<<1, 256, 0, stream>>>(partials, absum);
  k_conv1m<<<1024, 256, 0, stream>>>(x, qw1b, absum, p1t, s1, q1);
  k_conv2m<<<1024, 256, 0, stream>>>(p1t, qw2b, absum, s1, q1, g1, b1, p2, s2, q2);
  k_bn2<<<4096, 256, 0, stream>>>(p2, s2, q2, g2, b2);
  k_fc1m<<<dim3(8, 2, 16), 256, 0, stream>>>(p2, qfc1b, absum, h3p);
  k_fin3f<<<dim3(8, 8), 256, 0, stream>>>(h3p, h3, s3, q3);
  k_fc2<<<1024, 64, 0, stream>>>(h3, qwfc2, absum, s3, q3, g3, b3, out);
}

// Round 12
// 281.416 us; speedup vs baseline: 2.0199x; 2.0199x over previous
//
#include <hip/hip_runtime.h>
#include <stdint.h>

typedef unsigned short u16;
typedef unsigned int u32;
typedef __attribute__((ext_vector_type(8))) short s8v;   // 8 bf16 = 4 VGPR (MFMA A/B frag)
typedef __attribute__((ext_vector_type(4))) float f4v;   // MFMA C/D frag
typedef __attribute__((ext_vector_type(8))) u16 u16x8;

// ---------- bf16 helpers ----------
__device__ __forceinline__ float bf2f(u16 u){
  union { u32 i; float f; } v; v.i = ((u32)u) << 16; return v.f;
}
__device__ __forceinline__ u16 f2bf(float f){
  union { float f; u32 i; } v; v.f = f;
  u32 i = v.i;
  return (u16)((i + 0x7fffu + ((i >> 16) & 1u)) >> 16); // RNE
}
__device__ __forceinline__ float sgnf(float w){
  return (w > 0.f) ? 1.f : ((w < 0.f) ? -1.f : 0.f);
}
__device__ __forceinline__ u16 sgn_bf(float w){
  return (w > 0.f) ? (u16)0x3F80 : ((w < 0.f) ? (u16)0xBF80 : (u16)0);
}

// ---------- generate all quantized weight forms + fused absum partials ----------
__global__ __launch_bounds__(256) void k_signgen(const float* __restrict__ w1, const float* __restrict__ w2,
                                                 const float* __restrict__ wfc1, const float* __restrict__ wfc2,
                                                 u16* __restrict__ qw1b, u16* __restrict__ qw2b,
                                                 u16* __restrict__ qfc1b, float* __restrict__ qwfc2,
                                                 float* __restrict__ partials){
  int i = blockIdx.x * 256 + threadIdx.x;
  float av = 0.f; int slot;
  if (i < 2097152){
    int j = i & 7, lane = (i >> 3) & 63, fid = i >> 9;
    int kstep = fid >> 4, nt = fid & 15;
    int co = nt*16 + (lane & 15);
    int k_phys = kstep*32 + (lane >> 4)*8 + j;
    int px = k_phys >> 7, c = k_phys & 127;
    float wv = wfc1[(size_t)co*8192 + c*64 + px];
    qfc1b[i] = sgn_bf(wv);
    av = fabsf(wv); slot = 2;
  } else if (i < 2097152 + 73728){
    int i2 = i - 2097152;
    int j = i2 & 7, lane = (i2 >> 3) & 63, fid = i2 >> 9;  // 0..143
    int s = fid >> 4, ks = (fid >> 3) & 1, nt = fid & 7;
    int co = (lane & 15)*8 + nt;
    int c = ks*32 + (lane >> 4)*8 + j;
    float wv = w2[((size_t)co*64 + c)*9 + s];
    qw2b[i2] = sgn_bf(wv);
    av = fabsf(wv); slot = 1;
  } else if (i < 2097152 + 73728 + 2048){
    int i3 = i - (2097152 + 73728);
    int j = i3 & 7, lane = (i3 >> 3) & 63, nt = i3 >> 9;   // 0..3
    int co = nt*16 + (lane & 15);
    int k = (lane >> 4)*8 + j;
    if (k < 27){
      float wv = w1[co*27 + k];
      qw1b[i3] = sgn_bf(wv);
      av = fabsf(wv);
    } else qw1b[i3] = (u16)0;
    slot = 0;
  } else {
    int i4 = i - (2097152 + 73728 + 2048);
    float wv = wfc2[i4];
    qwfc2[i4] = sgnf(wv);
    av = fabsf(wv); slot = 3;
  }
  #pragma unroll
  for (int off = 32; off > 0; off >>= 1) av += __shfl_xor(av, off);
  if ((threadIdx.x & 63) == 0) atomicAdd(partials + slot*256 + (blockIdx.x & 255), av);
}

// ---------- reduce 4x256 partials -> absum[4] ----------
__global__ void k_red4(const float* __restrict__ partials, float* __restrict__ absum){
  int t = threadIdx.x, w = t >> 6, lane = t & 63;
  const float* p = partials + w*256;
  float s = p[lane] + p[lane + 64] + p[lane + 128] + p[lane + 192];
  #pragma unroll
  for (int off = 32; off > 0; off >>= 1) s += __shfl_xor(s, off);
  if (lane == 0) absum[w] = s;
}

// ---------- conv1 via MFMA: im2col in LDS + fused BN1 stats + in-lane 2x2 pool ----------
__global__ __launch_bounds__(256) void k_conv1m(const float* __restrict__ x, const u16* __restrict__ qw1b,
                                                const float* __restrict__ absum, u16* __restrict__ p1raw,
                                                float* __restrict__ gs, float* __restrict__ gq){
  __shared__ float xs[3*34*36];              // fp32 halo image, data y=1..32, x=2..33
  __shared__ __align__(16) u16 acol[256*40]; // im2col chunk: 256 rows x 40 u16 (32 used)
  __shared__ float ls1[64], ls2[64];
  int n = blockIdx.x, t = threadIdx.x;
  if (t < 64){ ls1[t] = 0.f; ls2[t] = 0.f; }
  for (int i = t; i < 3672; i += 256) xs[i] = 0.f;
  __syncthreads();
  const float4* xg = (const float4*)(x + (size_t)n * 3072);
  for (int i = t; i < 768; i += 256){
    float4 v = xg[i];
    int ci = i >> 8, rem = i & 255, y = rem >> 3, xq = (rem & 7) * 4;
    int base = ci*1224 + (y+1)*36 + 2 + xq;
    xs[base+0] = v.x; xs[base+1] = v.y; xs[base+2] = v.z; xs[base+3] = v.w;
  }
  int w = t >> 6, lane = t & 63, l15 = lane & 15, q = lane >> 4;
  const s8v* bp = (const s8v*)qw1b;
  s8v bf[4];
  #pragma unroll
  for (int nt = 0; nt < 4; ++nt) bf[nt] = bp[nt*64 + lane];
  float alpha = absum[0] * (1.f/1728.f);
  u16* p1img = p1raw + (size_t)n * 16384;
  float s1v[4], s2v[4];
  #pragma unroll
  for (int nt = 0; nt < 4; ++nt){ s1v[nt] = 0.f; s2v[nt] = 0.f; }
  for (int chunk = 0; chunk < 4; ++chunk){
    __syncthreads();
    {
      int mg = chunk*256 + t;
      int g = mg >> 2, s = mg & 3;
      int iy = 2*(g >> 4) + (s >> 1), ix = 2*(g & 15) + (s & 1);
      const float* xb = xs + iy*36 + ix + 1;
      u32 pk2[16];
      #pragma unroll
      for (int kk = 0; kk < 16; ++kk){
        int k0 = 2*kk, k1 = 2*kk + 1;
        u32 lo = (k0 < 27) ? (u32)f2bf(xb[(k0/9)*1224 + ((k0%9)/3)*36 + (k0%3)]) : 0u;
        u32 hi = (k1 < 27) ? (u32)f2bf(xb[(k1/9)*1224 + ((k1%9)/3)*36 + (k1%3)]) : 0u;
        pk2[kk] = lo | (hi << 16);
      }
      u32* ar = (u32*)(acol + t*40);
      #pragma unroll
      for (int v = 0; v < 4; ++v)
        *(uint4*)(ar + v*4) = make_uint4(pk2[v*4], pk2[v*4+1], pk2[v*4+2], pk2[v*4+3]);
    }
    __syncthreads();
    #pragma unroll
    for (int i = 0; i < 4; ++i){
      int tl = w*4 + i;
      s8v av = *(const s8v*)(acol + (tl*16 + l15)*40 + q*8);
      int g = chunk*64 + tl*4 + q;
      u16* drow = p1img + g*64 + l15;
      #pragma unroll
      for (int nt = 0; nt < 4; ++nt){
        f4v c = (f4v)(0.0f);
        c = __builtin_amdgcn_mfma_f32_16x16x32_bf16(av, bf[nt], c, 0, 0, 0);
        s1v[nt] += c[0] + c[1] + c[2] + c[3];
        s2v[nt] += c[0]*c[0] + c[1]*c[1] + c[2]*c[2] + c[3]*c[3];
        float pm = fmaxf(fmaxf(c[0], c[1]), fmaxf(c[2], c[3]));
        drow[nt*16] = f2bf(pm * alpha);
      }
    }
  }
  #pragma unroll
  for (int nt = 0; nt < 4; ++nt){
    s1v[nt] += __shfl_xor(s1v[nt], 16); s1v[nt] += __shfl_xor(s1v[nt], 32);
    s2v[nt] += __shfl_xor(s2v[nt], 16); s2v[nt] += __shfl_xor(s2v[nt], 32);
  }
  if (q == 0){
    #pragma unroll
    for (int nt = 0; nt < 4; ++nt){
      atomicAdd(&ls1[nt*16 + l15], s1v[nt]);
      atomicAdd(&ls2[nt*16 + l15], s2v[nt]);
    }
  }
  __syncthreads();
  if (t < 64){
    atomicAdd(gs + t, ls1[t] * alpha);
    atomicAdd(gq + t, ls2[t] * alpha * alpha);
  }
}

// ---------- conv2 via MFMA: R10 inner structure (acc[4][8] = the proven register shape;
// R11's acc[16][2] nt-split spilled ~800 MB) + per-shift LDS B-staging to kill the
// L1-bound redundant B streams (R10: 9.4 MB/CU through L1 ~= the whole 151k-cyc wall;
// now each block loads each B frag once -> 576 KB/CU, waves re-read from LDS).
// BN1 inline staging; in-register 2x2 pool; BN2 stats via bsh-overlay + global atomics.
__global__ __launch_bounds__(256, 2) void k_conv2m(const u16* __restrict__ p1raw, const u16* __restrict__ qw2b,
                                                   const float* __restrict__ absum,
                                                   const float* __restrict__ s1, const float* __restrict__ q1,
                                                   const float* __restrict__ g1, const float* __restrict__ b1,
                                                   u16* __restrict__ p2raw,
                                                   float* __restrict__ gs, float* __restrict__ gq){
  __shared__ __align__(16) u16 img[16384];   // 32 KB activations (XOR-swizzled 16B units)
  __shared__ __align__(16) u16 bsh[8192];    // 16 KB: B frags for current shift; stats overlay later
  int n = blockIdx.x, t = threadIdx.x;
  int c0 = (t & 7) * 8;
  float scv[8], biv[8];
  #pragma unroll
  for (int j = 0; j < 8; ++j){
    float m = s1[c0+j] * (1.f/1048576.f);
    float var = q1[c0+j] * (1.f/1048576.f) - m*m;
    float sc = g1[c0+j] * rsqrtf(var + 1e-5f);
    scv[j] = sc; biv[j] = b1[c0+j] - m*sc;
  }
  const u16* src = p1raw + (size_t)n * 16384;
  #pragma unroll
  for (int i = 0; i < 8; ++i){
    int id = i*256 + t;            // = px*8 + unit, unit == t&7
    int px = id >> 3, unit = id & 7;
    int su = unit ^ (px & 7);
    u16x8 v = *(const u16x8*)(src + id*8);
    u16x8 o;
    #pragma unroll
    for (int j = 0; j < 8; ++j)
      o[j] = f2bf(fmaxf(bf2f(v[j]) * scv[j] + biv[j], 0.f));
    *(u16x8*)(img + px*64 + su*8) = o;
  }
  int w = t >> 6, lane = t & 63, l15 = lane & 15, q = lane >> 4;
  const u16x8* bpv = (const u16x8*)qw2b;     // global B table, 16B units (1024 units/shift)
  u16x8* bshv = (u16x8*)bsh;
  const s8v* bsv = (const s8v*)bsh;
  f4v acc[4][8];
  #pragma unroll
  for (int a = 0; a < 4; ++a)
    #pragma unroll
    for (int b = 0; b < 8; ++b) acc[a][b] = (f4v)(0.0f);
  for (int dy = 0; dy < 3; ++dy){
    for (int dx = 0; dx < 3; ++dx){
      int s = dy*3 + dx;
      __syncthreads();             // prior-shift B reads done (iter 0: also orders img writes)
      #pragma unroll
      for (int i = 0; i < 4; ++i) bshv[i*256 + t] = bpv[s*1024 + i*256 + t];
      __syncthreads();             // B slice + img visible
      int xv = l15 + dx - 1;
      bool vx = (xv >= 0) && (xv < 16);
      int xc = min(max(xv, 0), 15);
      #pragma unroll
      for (int ks = 0; ks < 2; ++ks){
        s8v bf[8];
        #pragma unroll
        for (int nt = 0; nt < 8; ++nt) bf[nt] = bsv[(ks*8 + nt)*64 + lane];
        #pragma unroll
        for (int mt = 0; mt < 4; ++mt){
          int yv = w*4 + mt + dy - 1;
          if (yv < 0 || yv > 15) continue;
          int px = yv*16 + xc;
          int su = (ks*4 + q) ^ (px & 7);
          s8v av = *(const s8v*)(img + px*64 + su*8);
          if (!vx) av = (s8v)(short)0;
          #pragma unroll
          for (int nt = 0; nt < 8; ++nt)
            acc[mt][nt] = __builtin_amdgcn_mfma_f32_16x16x32_bf16(av, bf[nt], acc[mt][nt], 0, 0, 0);
        }
      }
    }
  }
  float alpha = absum[1] * (1.f/73728.f);
  float s1v[8], s2v[8];
  #pragma unroll
  for (int nt = 0; nt < 8; ++nt){ s1v[nt] = 0.f; s2v[nt] = 0.f; }
  // in-register 2x2 pool: this wave's rows w*4..w*4+3 pair into pooled rows w*2, w*2+1
  #pragma unroll
  for (int mp = 0; mp < 2; ++mp){
    #pragma unroll
    for (int rp = 0; rp < 2; ++rp){
      u16x8 pk;
      #pragma unroll
      for (int nt = 0; nt < 8; ++nt){
        float v0 = acc[2*mp][nt][2*rp]     * alpha;
        float v1 = acc[2*mp][nt][2*rp+1]   * alpha;
        float v2 = acc[2*mp+1][nt][2*rp]   * alpha;
        float v3 = acc[2*mp+1][nt][2*rp+1] * alpha;
        s1v[nt] += v0 + v1 + v2 + v3;
        s2v[nt] += v0*v0 + v1*v1 + v2*v2 + v3*v3;
        pk[nt] = f2bf(fmaxf(fmaxf(v0, v1), fmaxf(v2, v3)));
      }
      int opx = (w*2 + mp)*8 + (q*2 + rp);  // pooled 8x8 index
      *(u16x8*)(p2raw + ((size_t)n*64 + opx)*128 + l15*8) = pk;
    }
  }
  #pragma unroll
  for (int nt = 0; nt < 8; ++nt){
    s1v[nt] += __shfl_xor(s1v[nt], 16); s1v[nt] += __shfl_xor(s1v[nt], 32);
    s2v[nt] += __shfl_xor(s2v[nt], 16); s2v[nt] += __shfl_xor(s2v[nt], 32);
  }
  __syncthreads();                 // all waves done with bsh -> reuse as stats LDS
  float* ls = (float*)bsh;         // ls[0..127]=sum, ls[128..255]=sumsq
  if (t < 256) ls[t] = 0.f;
  __syncthreads();
  if (q == 0){
    #pragma unroll
    for (int nt = 0; nt < 8; ++nt){
      atomicAdd(&ls[l15*8 + nt], s1v[nt]);
      atomicAdd(&ls[128 + l15*8 + nt], s2v[nt]);
    }
  }
  __syncthreads();
  if (t < 128){ atomicAdd(gs + t, ls[t]); atomicAdd(gq + t, ls[128 + t]); }
}

// ---------- BN2 affine + ReLU in-place on p2[1024][64px][128c] (params inline) ----------
__global__ __launch_bounds__(256) void k_bn2(u16* __restrict__ p2,
                                             const float* __restrict__ s2, const float* __restrict__ q2,
                                             const float* __restrict__ g2, const float* __restrict__ b2){
  size_t i = (size_t)blockIdx.x * 256 + threadIdx.x;   // unit of 8 u16
  int c0 = ((int)(i & 15)) * 8;
  float scv[8], biv[8];
  #pragma unroll
  for (int j = 0; j < 8; ++j){
    float m = s2[c0+j] * (1.f/262144.f);
    float var = q2[c0+j] * (1.f/262144.f) - m*m;
    float sc = g2[c0+j] * rsqrtf(var + 1e-5f);
    scv[j] = sc; biv[j] = b2[c0+j] - m*sc;
  }
  u16x8 v = *(u16x8*)(p2 + i*8);
  u16x8 o;
  #pragma unroll
  for (int j = 0; j < 8; ++j)
    o[j] = f2bf(fmaxf(bf2f(v[j]) * scv[j] + biv[j], 0.f));
  *(u16x8*)(p2 + i*8) = o;
}

// ---------- fc1 via MFMA, k-split 16: p2[1024][8192] x signs -> h3p[16][1024][256] ----------
__global__ __launch_bounds__(256) void k_fc1m(const u16* __restrict__ p2, const u16* __restrict__ qfc1b,
                                              const float* __restrict__ absum, float* __restrict__ h3p){
  int t = threadIdx.x;
  int bm = blockIdx.x, bn = blockIdx.y, kb = blockIdx.z;
  int w = t >> 6, lane = t & 63, l15 = lane & 15, q = lane >> 4;
  int rowbase = bm*128 + (w >> 1)*64;
  int ntb = bn*8 + (w & 1)*4;
  const s8v* bp = (const s8v*)qfc1b;
  f4v acc[4][4];
  #pragma unroll
  for (int a = 0; a < 4; ++a)
    #pragma unroll
    for (int b = 0; b < 4; ++b) acc[a][b] = (f4v)(0.0f);
  #pragma unroll 2
  for (int ks = 0; ks < 16; ++ks){
    int kst = kb*16 + ks;
    s8v bf[4], af[4];
    #pragma unroll
    for (int nt = 0; nt < 4; ++nt) bf[nt] = bp[(kst*16 + ntb + nt)*64 + lane];
    #pragma unroll
    for (int mt = 0; mt < 4; ++mt)
      af[mt] = *(const s8v*)(p2 + (size_t)(rowbase + mt*16 + l15)*8192 + kst*32 + q*8);
    #pragma unroll
    for (int mt = 0; mt < 4; ++mt)
      #pragma unroll
      for (int nt = 0; nt < 4; ++nt)
        acc[mt][nt] = __builtin_amdgcn_mfma_f32_16x16x32_bf16(af[mt], bf[nt], acc[mt][nt], 0, 0, 0);
  }
  float alpha = absum[2] * (1.f/2097152.f);
  float* dst = h3p + (size_t)kb * 262144;
  #pragma unroll
  for (int mt = 0; mt < 4; ++mt)
    #pragma unroll
    for (int nt = 0; nt < 4; ++nt){
      int col = (ntb + nt)*16 + l15;
      #pragma unroll
      for (int r = 0; r < 4; ++r)
        dst[(size_t)(rowbase + mt*16 + q*4 + r)*256 + col] = acc[mt][nt][r] * alpha;
    }
}

// ---------- reduce k-split slabs + BN3 stats + materialize h3 ----------
__global__ __launch_bounds__(256) void k_fin3f(const float* __restrict__ h3p, float* __restrict__ h3,
                                               float* __restrict__ s3, float* __restrict__ q3){
  int jb = blockIdx.x, ns = blockIdx.y, t = threadIdx.x;
  int jj = t & 31, nn = t >> 5;
  int j = jb*32 + jj;
  float s1 = 0.f, s2 = 0.f;
  for (int i = nn; i < 128; i += 8){
    int n = i*8 + ns;
    float v = 0.f;
    #pragma unroll 8
    for (int kb = 0; kb < 16; ++kb) v += h3p[(size_t)kb*262144 + n*256 + j];
    h3[n*256 + j] = v;
    s1 += v; s2 += v*v;
  }
  __shared__ float l1[256], l2[256];
  l1[t] = s1; l2[t] = s2;
  __syncthreads();
  if (t < 32){
    float a = 0.f, b = 0.f;
    #pragma unroll
    for (int k = 0; k < 8; ++k){ a += l1[t+32*k]; b += l2[t+32*k]; }
    atomicAdd(s3 + jb*32 + t, a); atomicAdd(q3 + jb*32 + t, b);
  }
}

// ---------- fc2: relu(bn3(h3)) @ sign(wfc2)^T -> out[1024,10] fp32 (BN3 params inline) ----------
__global__ __launch_bounds__(64) void k_fc2(const float* __restrict__ h3, const float* __restrict__ qwfc2,
                                            const float* __restrict__ absum,
                                            const float* __restrict__ s3, const float* __restrict__ q3,
                                            const float* __restrict__ g3, const float* __restrict__ b3,
                                            float* __restrict__ out){
  int n = blockIdx.x, lane = threadIdx.x;
  float a[4];
  #pragma unroll
  for (int i = 0; i < 4; ++i){
    int j = lane + 64*i;
    float m = s3[j] * (1.f/1024.f);
    float var = q3[j] * (1.f/1024.f) - m*m;
    float sc = g3[j] * rsqrtf(var + 1e-5f);
    float v = h3[(size_t)n*256 + j] * sc + (b3[j] - m*sc);
    a[i] = fmaxf(v, 0.f);
  }
  float alpha = absum[3] * (1.f/2560.f);
  #pragma unroll
  for (int k = 0; k < 10; ++k){
    float p = 0.f;
    #pragma unroll
    for (int i = 0; i < 4; ++i) p += a[i] * qwfc2[k*256 + lane + 64*i];
    #pragma unroll
    for (int off = 32; off > 0; off >>= 1) p += __shfl_down(p, off);
    if (lane == 0) out[n*10 + k] = p * alpha;
  }
}

extern "C" void kernel_launch(void* const* d_in, const int* in_sizes, int n_in,
                              void* d_out, int out_size, void* d_ws, size_t ws_size,
                              hipStream_t stream){
  (void)in_sizes; (void)n_in; (void)out_size; (void)ws_size;
  const float* x    = (const float*)d_in[0];
  const float* w1   = (const float*)d_in[1];
  const float* g1   = (const float*)d_in[2];
  const float* b1   = (const float*)d_in[3];
  const float* w2   = (const float*)d_in[4];
  const float* g2   = (const float*)d_in[5];
  const float* b2   = (const float*)d_in[6];
  const float* wfc1 = (const float*)d_in[7];
  const float* g3   = (const float*)d_in[8];
  const float* b3   = (const float*)d_in[9];
  const float* wfc2 = (const float*)d_in[10];
  float* out = (float*)d_out;

  float* wsf = (float*)d_ws;
  char*  wsb = (char*)d_ws;
  float* absum = wsf;
  float* s1 = wsf + 16;   float* q1 = wsf + 80;
  float* s2 = wsf + 144;  float* q2 = wsf + 272;
  float* s3 = wsf + 1024; float* q3 = wsf + 1280;
  float* partials = wsf + 2048;                      // 4x256 fp32 (zeroed)
  u16*   qw1b  = (u16*)(wsf + 4096);                 // 2048 u16 conv1 B-frags
  u16*   qw2b  = (u16*)(wsb + (64u << 10));          // 144 KB bf16 B-frags
  float* qwfc2 = (float*)(wsb + (256u << 10));       // 10 KB fp32
  float* h3    = (float*)(wsb + (1ull << 20));       // 1 MB fp32 [1024][256]
  u16*   qfc1b = (u16*)(wsb + (2ull << 20));         // 4 MB bf16 B-frags
  u16*   p1t   = (u16*)(wsb + (8ull << 20) + 4096);  // 32 MB bf16 [1024][256][64]
  u16*   p2    = (u16*)(wsb + (112ull << 20));       // 16 MB bf16 [1024][64][128] pooled raw -> bn2 in place
  float* h3p   = (float*)(wsb + (128ull << 20));     // 16 MB fp32 [16][1024][256]

  hipMemsetAsync(wsf, 0, 3072 * sizeof(float), stream);
  k_signgen<<<8498, 256, 0, stream>>>(w1, w2, wfc1, wfc2, qw1b, qw2b, qfc1b, qwfc2, partials);
  k_red4<<<1, 256, 0, stream>>>(partials, absum);
  k_conv1m<<<1024, 256, 0, stream>>>(x, qw1b, absum, p1t, s1, q1);
  k_conv2m<<<1024, 256, 0, stream>>>(p1t, qw2b, absum, s1, q1, g1, b1, p2, s2, q2);
  k_bn2<<<4096, 256, 0, stream>>>(p2, s2, q2, g2, b2);
  k_fc1m<<<dim3(8, 2, 16), 256, 0, stream>>>(p2, qfc1b, absum, h3p);
  k_fin3f<<<dim3(8, 8), 256, 0, stream>>>(h3p, h3, s3, q3);
  k_fc2<<<1024, 64, 0, stream>>>(h3, qwfc2, absum, s3, q3, g3, b3, out);
}

// Round 13
// 260.836 us; speedup vs baseline: 2.1793x; 1.0789x over previous
//
#include <hip/hip_runtime.h>
#include <stdint.h>

typedef unsigned short u16;
typedef unsigned int u32;
typedef __attribute__((ext_vector_type(8))) short s8v;   // 8 bf16 = 4 VGPR (MFMA A/B frag)
typedef __attribute__((ext_vector_type(4))) float f4v;   // MFMA C/D frag
typedef __attribute__((ext_vector_type(8))) u16 u16x8;
typedef __attribute__((ext_vector_type(4))) u16 u16x4;

// ---------- bf16 helpers ----------
__device__ __forceinline__ float bf2f(u16 u){
  union { u32 i; float f; } v; v.i = ((u32)u) << 16; return v.f;
}
__device__ __forceinline__ u16 f2bf(float f){
  union { float f; u32 i; } v; v.f = f;
  u32 i = v.i;
  return (u16)((i + 0x7fffu + ((i >> 16) & 1u)) >> 16); // RNE
}
__device__ __forceinline__ float sgnf(float w){
  return (w > 0.f) ? 1.f : ((w < 0.f) ? -1.f : 0.f);
}
__device__ __forceinline__ u16 sgn_bf(float w){
  return (w > 0.f) ? (u16)0x3F80 : ((w < 0.f) ? (u16)0xBF80 : (u16)0);
}

// ---------- sign-gen for the SMALL weights (w2, w1, wfc2) + absum partials ----------
// 78336 elements total; every region boundary is a multiple of 64 -> wave-uniform slot.
__global__ __launch_bounds__(256) void k_signgen_small(const float* __restrict__ w1, const float* __restrict__ w2,
                                                       const float* __restrict__ wfc2,
                                                       u16* __restrict__ qw1b, u16* __restrict__ qw2b,
                                                       float* __restrict__ qwfc2, float* __restrict__ partials){
  int i = blockIdx.x * 256 + threadIdx.x;
  float av = 0.f; int slot;
  if (i < 73728){
    int j = i & 7, lane = (i >> 3) & 63, fid = i >> 9;    // 0..143
    int s = fid >> 4, ks = (fid >> 3) & 1, nt = fid & 7;
    int co = (lane & 15)*8 + nt;
    int c = ks*32 + (lane >> 4)*8 + j;
    float wv = w2[((size_t)co*64 + c)*9 + s];
    qw2b[i] = sgn_bf(wv);
    av = fabsf(wv); slot = 1;
  } else if (i < 73728 + 2048){
    int i3 = i - 73728;
    int j = i3 & 7, lane = (i3 >> 3) & 63, nt = i3 >> 9;  // 0..3
    int co = nt*16 + (lane & 15);
    int k = (lane >> 4)*8 + j;
    if (k < 27){
      float wv = w1[co*27 + k];
      qw1b[i3] = sgn_bf(wv);
      av = fabsf(wv);
    } else qw1b[i3] = (u16)0;
    slot = 0;
  } else {
    int i4 = i - (73728 + 2048);
    float wv = wfc2[i4];
    qwfc2[i4] = sgnf(wv);
    av = fabsf(wv); slot = 3;
  }
  #pragma unroll
  for (int off = 32; off > 0; off >>= 1) av += __shfl_xor(av, off);
  if ((threadIdx.x & 63) == 0) atomicAdd(partials + slot*256 + (blockIdx.x & 255), av);
}

// ---------- wfc1 sign + k-permute via LDS transpose (R12 post-mortem: the direct gather
// read wfc1 at 256B stride -> ~2M distinct 64B lines = ~128 MB effective traffic).
// One block per co row: coalesced float4 reads -> c-major LDS tile -> chunk writes. ----------
__global__ __launch_bounds__(256) void k_fc1gen(const float* __restrict__ wfc1, u16* __restrict__ qfc1b,
                                                float* __restrict__ partials){
  __shared__ u16 tile[128*72];   // [c][px], row pad 64->72 (18 KB)
  int co = blockIdx.x, t = threadIdx.x;
  const float4* src = (const float4*)(wfc1 + (size_t)co*8192);
  float av = 0.f;
  #pragma unroll
  for (int p = 0; p < 8; ++p){
    int k4 = t + p*256;              // float4 index; k_src = k4*4
    float4 v = src[k4];
    int c = k4 >> 4, px = (k4 & 15)*4;   // k_src>>6, k_src&63
    u16* d = tile + c*72 + px;
    d[0] = sgn_bf(v.x); d[1] = sgn_bf(v.y); d[2] = sgn_bf(v.z); d[3] = sgn_bf(v.w);
    av += fabsf(v.x) + fabsf(v.y) + fabsf(v.z) + fabsf(v.w);
  }
  #pragma unroll
  for (int off = 32; off > 0; off >>= 1) av += __shfl_xor(av, off);
  if ((t & 63) == 0) atomicAdd(partials + 2*256 + (co & 255), av);
  __syncthreads();
  // write 1024 chunks of 8 u16 in dest (k_phys) order
  int co4 = co >> 4, co15 = co & 15;
  #pragma unroll
  for (int p = 0; p < 4; ++p){
    int m = t + p*256;               // chunk id = px*16 + jj
    int px = m >> 4, jj = m & 15;
    int kstep = px*4 + (jj >> 2), l16 = jj & 3;
    u16x8 o;
    #pragma unroll
    for (int u = 0; u < 8; ++u) o[u] = tile[(jj*8 + u)*72 + px];
    *(u16x8*)(qfc1b + ((size_t)(kstep*16 + co4)*512 + (l16*16 + co15)*8)) = o;
  }
}

// ---------- reduce 4x256 partials -> absum[4] ----------
__global__ void k_red4(const float* __restrict__ partials, float* __restrict__ absum){
  int t = threadIdx.x, w = t >> 6, lane = t & 63;
  const float* p = partials + w*256;
  float s = p[lane] + p[lane + 64] + p[lane + 128] + p[lane + 192];
  #pragma unroll
  for (int off = 32; off > 0; off >>= 1) s += __shfl_xor(s, off);
  if (lane == 0) absum[w] = s;
}

// ---------- conv1 via MFMA: im2col in LDS + fused BN1 stats + in-lane 2x2 pool ----------
__global__ __launch_bounds__(256) void k_conv1m(const float* __restrict__ x, const u16* __restrict__ qw1b,
                                                const float* __restrict__ absum, u16* __restrict__ p1raw,
                                                float* __restrict__ gs, float* __restrict__ gq){
  __shared__ float xs[3*34*36];              // fp32 halo image, data y=1..32, x=2..33
  __shared__ __align__(16) u16 acol[256*40]; // im2col chunk: 256 rows x 40 u16 (32 used)
  __shared__ float ls1[64], ls2[64];
  int n = blockIdx.x, t = threadIdx.x;
  if (t < 64){ ls1[t] = 0.f; ls2[t] = 0.f; }
  for (int i = t; i < 3672; i += 256) xs[i] = 0.f;
  __syncthreads();
  const float4* xg = (const float4*)(x + (size_t)n * 3072);
  for (int i = t; i < 768; i += 256){
    float4 v = xg[i];
    int ci = i >> 8, rem = i & 255, y = rem >> 3, xq = (rem & 7) * 4;
    int base = ci*1224 + (y+1)*36 + 2 + xq;
    xs[base+0] = v.x; xs[base+1] = v.y; xs[base+2] = v.z; xs[base+3] = v.w;
  }
  int w = t >> 6, lane = t & 63, l15 = lane & 15, q = lane >> 4;
  const s8v* bp = (const s8v*)qw1b;
  s8v bf[4];
  #pragma unroll
  for (int nt = 0; nt < 4; ++nt) bf[nt] = bp[nt*64 + lane];
  float alpha = absum[0] * (1.f/1728.f);
  u16* p1img = p1raw + (size_t)n * 16384;
  float s1v[4], s2v[4];
  #pragma unroll
  for (int nt = 0; nt < 4; ++nt){ s1v[nt] = 0.f; s2v[nt] = 0.f; }
  for (int chunk = 0; chunk < 4; ++chunk){
    __syncthreads();
    {
      int mg = chunk*256 + t;
      int g = mg >> 2, s = mg & 3;
      int iy = 2*(g >> 4) + (s >> 1), ix = 2*(g & 15) + (s & 1);
      const float* xb = xs + iy*36 + ix + 1;
      u32 pk2[16];
      #pragma unroll
      for (int kk = 0; kk < 16; ++kk){
        int k0 = 2*kk, k1 = 2*kk + 1;
        u32 lo = (k0 < 27) ? (u32)f2bf(xb[(k0/9)*1224 + ((k0%9)/3)*36 + (k0%3)]) : 0u;
        u32 hi = (k1 < 27) ? (u32)f2bf(xb[(k1/9)*1224 + ((k1%9)/3)*36 + (k1%3)]) : 0u;
        pk2[kk] = lo | (hi << 16);
      }
      u32* ar = (u32*)(acol + t*40);
      #pragma unroll
      for (int v = 0; v < 4; ++v)
        *(uint4*)(ar + v*4) = make_uint4(pk2[v*4], pk2[v*4+1], pk2[v*4+2], pk2[v*4+3]);
    }
    __syncthreads();
    #pragma unroll
    for (int i = 0; i < 4; ++i){
      int tl = w*4 + i;
      s8v av = *(const s8v*)(acol + (tl*16 + l15)*40 + q*8);
      int g = chunk*64 + tl*4 + q;
      u16* drow = p1img + g*64 + l15;
      #pragma unroll
      for (int nt = 0; nt < 4; ++nt){
        f4v c = (f4v)(0.0f);
        c = __builtin_amdgcn_mfma_f32_16x16x32_bf16(av, bf[nt], c, 0, 0, 0);
        s1v[nt] += c[0] + c[1] + c[2] + c[3];
        s2v[nt] += c[0]*c[0] + c[1]*c[1] + c[2]*c[2] + c[3]*c[3];
        float pm = fmaxf(fmaxf(c[0], c[1]), fmaxf(c[2], c[3]));
        drow[nt*16] = f2bf(pm * alpha);
      }
    }
  }
  #pragma unroll
  for (int nt = 0; nt < 4; ++nt){
    s1v[nt] += __shfl_xor(s1v[nt], 16); s1v[nt] += __shfl_xor(s1v[nt], 32);
    s2v[nt] += __shfl_xor(s2v[nt], 16); s2v[nt] += __shfl_xor(s2v[nt], 32);
  }
  if (q == 0){
    #pragma unroll
    for (int nt = 0; nt < 4; ++nt){
      atomicAdd(&ls1[nt*16 + l15], s1v[nt]);
      atomicAdd(&ls2[nt*16 + l15], s2v[nt]);
    }
  }
  __syncthreads();
  if (t < 64){
    atomicAdd(gs + t, ls1[t] * alpha);
    atomicAdd(gq + t, ls2[t] * alpha * alpha);
  }
}

// ---------- conv2 via MFMA, per-block co-HALF split (R12 post-mortem: 1024-block grid was
// concurrency-starved -- Occupancy 16%, no pipe >22%; LDS B-staging was neutral so B path
// is NOT the limiter). Grid (1024, 2): block (n, h) computes co = l15*8 + h*4 + nt (nt<4)
// with R10's proven wave shape (rows w*4..w*4+3, acc[4][4], global B loads, 1 barrier).
// BN1 inline staging; in-register 2x2 pool; BN2 stats via img-overlay + global atomics.
__global__ __launch_bounds__(256, 2) void k_conv2m(const u16* __restrict__ p1raw, const u16* __restrict__ qw2b,
                                                   const float* __restrict__ absum,
                                                   const float* __restrict__ s1, const float* __restrict__ q1,
                                                   const float* __restrict__ g1, const float* __restrict__ b1,
                                                   u16* __restrict__ p2raw,
                                                   float* __restrict__ gs, float* __restrict__ gq){
  __shared__ __align__(16) u16 img[16384];   // 32 KB exactly; stats overlay after compute
  int n = blockIdx.x, h = blockIdx.y, t = threadIdx.x;
  int c0 = (t & 7) * 8;
  float scv[8], biv[8];
  #pragma unroll
  for (int j = 0; j < 8; ++j){
    float m = s1[c0+j] * (1.f/1048576.f);
    float var = q1[c0+j] * (1.f/1048576.f) - m*m;
    float sc = g1[c0+j] * rsqrtf(var + 1e-5f);
    scv[j] = sc; biv[j] = b1[c0+j] - m*sc;
  }
  const u16* src = p1raw + (size_t)n * 16384;
  #pragma unroll
  for (int i = 0; i < 8; ++i){
    int id = i*256 + t;            // = px*8 + unit, unit == t&7
    int px = id >> 3, unit = id & 7;
    int su = unit ^ (px & 7);
    u16x8 v = *(const u16x8*)(src + id*8);
    u16x8 o;
    #pragma unroll
    for (int j = 0; j < 8; ++j)
      o[j] = f2bf(fmaxf(bf2f(v[j]) * scv[j] + biv[j], 0.f));
    *(u16x8*)(img + px*64 + su*8) = o;
  }
  __syncthreads();
  int w = t >> 6, lane = t & 63, l15 = lane & 15, q = lane >> 4;
  const s8v* bp = (const s8v*)qw2b;
  f4v acc[4][4];
  #pragma unroll
  for (int a = 0; a < 4; ++a)
    #pragma unroll
    for (int b = 0; b < 4; ++b) acc[a][b] = (f4v)(0.0f);
  #pragma unroll
  for (int dy = 0; dy < 3; ++dy){
    #pragma unroll
    for (int dx = 0; dx < 3; ++dx){
      int s = dy*3 + dx;
      int xv = l15 + dx - 1;
      bool vx = (xv >= 0) && (xv < 16);
      int xc = min(max(xv, 0), 15);
      #pragma unroll
      for (int ks = 0; ks < 2; ++ks){
        s8v bf[4];
        #pragma unroll
        for (int nt = 0; nt < 4; ++nt) bf[nt] = bp[((s*2 + ks)*8 + h*4 + nt)*64 + lane];
        #pragma unroll
        for (int mt = 0; mt < 4; ++mt){
          int yv = w*4 + mt + dy - 1;
          if (yv < 0 || yv > 15) continue;
          int px = yv*16 + xc;
          int su = (ks*4 + q) ^ (px & 7);
          s8v av = *(const s8v*)(img + px*64 + su*8);
          if (!vx) av = (s8v)(short)0;
          #pragma unroll
          for (int nt = 0; nt < 4; ++nt)
            acc[mt][nt] = __builtin_amdgcn_mfma_f32_16x16x32_bf16(av, bf[nt], acc[mt][nt], 0, 0, 0);
        }
      }
    }
  }
  float alpha = absum[1] * (1.f/73728.f);
  float s1v[4], s2v[4];
  #pragma unroll
  for (int nt = 0; nt < 4; ++nt){ s1v[nt] = 0.f; s2v[nt] = 0.f; }
  // in-register 2x2 pool: rows w*4..w*4+3 pair into pooled rows w*2, w*2+1
  #pragma unroll
  for (int mp = 0; mp < 2; ++mp){
    #pragma unroll
    for (int rp = 0; rp < 2; ++rp){
      u16x4 pk;
      #pragma unroll
      for (int nt = 0; nt < 4; ++nt){
        float v0 = acc[2*mp][nt][2*rp]     * alpha;
        float v1 = acc[2*mp][nt][2*rp+1]   * alpha;
        float v2 = acc[2*mp+1][nt][2*rp]   * alpha;
        float v3 = acc[2*mp+1][nt][2*rp+1] * alpha;
        s1v[nt] += v0 + v1 + v2 + v3;
        s2v[nt] += v0*v0 + v1*v1 + v2*v2 + v3*v3;
        pk[nt] = f2bf(fmaxf(fmaxf(v0, v1), fmaxf(v2, v3)));
      }
      int opx = (w*2 + mp)*8 + (q*2 + rp);  // pooled 8x8 index
      *(u16x4*)(p2raw + ((size_t)n*64 + opx)*128 + l15*8 + h*4) = pk;
    }
  }
  #pragma unroll
  for (int nt = 0; nt < 4; ++nt){
    s1v[nt] += __shfl_xor(s1v[nt], 16); s1v[nt] += __shfl_xor(s1v[nt], 32);
    s2v[nt] += __shfl_xor(s2v[nt], 16); s2v[nt] += __shfl_xor(s2v[nt], 32);
  }
  __syncthreads();                 // all waves done reading img -> reuse as stats LDS
  float* ls = (float*)img;         // ls[0..127]=sum, ls[128..255]=sumsq
  if (t < 256) ls[t] = 0.f;
  __syncthreads();
  if (q == 0){
    #pragma unroll
    for (int nt = 0; nt < 4; ++nt){
      int co = l15*8 + h*4 + nt;
      atomicAdd(&ls[co], s1v[nt]);
      atomicAdd(&ls[128 + co], s2v[nt]);
    }
  }
  __syncthreads();
  if (t < 128){
    if (ls[t] != 0.f || ls[128 + t] != 0.f){
      atomicAdd(gs + t, ls[t]); atomicAdd(gq + t, ls[128 + t]);
    }
  }
}

// ---------- BN2 affine + ReLU in-place on p2[1024][64px][128c] (params inline) ----------
__global__ __launch_bounds__(256) void k_bn2(u16* __restrict__ p2,
                                             const float* __restrict__ s2, const float* __restrict__ q2,
                                             const float* __restrict__ g2, const float* __restrict__ b2){
  size_t i = (size_t)blockIdx.x * 256 + threadIdx.x;   // unit of 8 u16
  int c0 = ((int)(i & 15)) * 8;
  float scv[8], biv[8];
  #pragma unroll
  for (int j = 0; j < 8; ++j){
    float m = s2[c0+j] * (1.f/262144.f);
    float var = q2[c0+j] * (1.f/262144.f) - m*m;
    float sc = g2[c0+j] * rsqrtf(var + 1e-5f);
    scv[j] = sc; biv[j] = b2[c0+j] - m*sc;
  }
  u16x8 v = *(u16x8*)(p2 + i*8);
  u16x8 o;
  #pragma unroll
  for (int j = 0; j < 8; ++j)
    o[j] = f2bf(fmaxf(bf2f(v[j]) * scv[j] + biv[j], 0.f));
  *(u16x8*)(p2 + i*8) = o;
}

// ---------- fc1 via MFMA, k-split 16: p2[1024][8192] x signs -> h3p[16][1024][256] ----------
__global__ __launch_bounds__(256) void k_fc1m(const u16* __restrict__ p2, const u16* __restrict__ qfc1b,
                                              const float* __restrict__ absum, float* __restrict__ h3p){
  int t = threadIdx.x;
  int bm = blockIdx.x, bn = blockIdx.y, kb = blockIdx.z;
  int w = t >> 6, lane = t & 63, l15 = lane & 15, q = lane >> 4;
  int rowbase = bm*128 + (w >> 1)*64;
  int ntb = bn*8 + (w & 1)*4;
  const s8v* bp = (const s8v*)qfc1b;
  f4v acc[4][4];
  #pragma unroll
  for (int a = 0; a < 4; ++a)
    #pragma unroll
    for (int b = 0; b < 4; ++b) acc[a][b] = (f4v)(0.0f);
  #pragma unroll 2
  for (int ks = 0; ks < 16; ++ks){
    int kst = kb*16 + ks;
    s8v bf[4], af[4];
    #pragma unroll
    for (int nt = 0; nt < 4; ++nt) bf[nt] = bp[(kst*16 + ntb + nt)*64 + lane];
    #pragma unroll
    for (int mt = 0; mt < 4; ++mt)
      af[mt] = *(const s8v*)(p2 + (size_t)(rowbase + mt*16 + l15)*8192 + kst*32 + q*8);
    #pragma unroll
    for (int mt = 0; mt < 4; ++mt)
      #pragma unroll
      for (int nt = 0; nt < 4; ++nt)
        acc[mt][nt] = __builtin_amdgcn_mfma_f32_16x16x32_bf16(af[mt], bf[nt], acc[mt][nt], 0, 0, 0);
  }
  float alpha = absum[2] * (1.f/2097152.f);
  float* dst = h3p + (size_t)kb * 262144;
  #pragma unroll
  for (int mt = 0; mt < 4; ++mt)
    #pragma unroll
    for (int nt = 0; nt < 4; ++nt){
      int col = (ntb + nt)*16 + l15;
      #pragma unroll
      for (int r = 0; r < 4; ++r)
        dst[(size_t)(rowbase + mt*16 + q*4 + r)*256 + col] = acc[mt][nt][r] * alpha;
    }
}

// ---------- reduce k-split slabs + BN3 stats + materialize h3 ----------
__global__ __launch_bounds__(256) void k_fin3f(const float* __restrict__ h3p, float* __restrict__ h3,
                                               float* __restrict__ s3, float* __restrict__ q3){
  int jb = blockIdx.x, ns = blockIdx.y, t = threadIdx.x;
  int jj = t & 31, nn = t >> 5;
  int j = jb*32 + jj;
  float s1 = 0.f, s2 = 0.f;
  for (int i = nn; i < 128; i += 8){
    int n = i*8 + ns;
    float v = 0.f;
    #pragma unroll 8
    for (int kb = 0; kb < 16; ++kb) v += h3p[(size_t)kb*262144 + n*256 + j];
    h3[n*256 + j] = v;
    s1 += v; s2 += v*v;
  }
  __shared__ float l1[256], l2[256];
  l1[t] = s1; l2[t] = s2;
  __syncthreads();
  if (t < 32){
    float a = 0.f, b = 0.f;
    #pragma unroll
    for (int k = 0; k < 8; ++k){ a += l1[t+32*k]; b += l2[t+32*k]; }
    atomicAdd(s3 + jb*32 + t, a); atomicAdd(q3 + jb*32 + t, b);
  }
}

// ---------- fc2: relu(bn3(h3)) @ sign(wfc2)^T -> out[1024,10] fp32 (BN3 params inline) ----------
__global__ __launch_bounds__(64) void k_fc2(const float* __restrict__ h3, const float* __restrict__ qwfc2,
                                            const float* __restrict__ absum,
                                            const float* __restrict__ s3, const float* __restrict__ q3,
                                            const float* __restrict__ g3, const float* __restrict__ b3,
                                            float* __restrict__ out){
  int n = blockIdx.x, lane = threadIdx.x;
  float a[4];
  #pragma unroll
  for (int i = 0; i < 4; ++i){
    int j = lane + 64*i;
    float m = s3[j] * (1.f/1024.f);
    float var = q3[j] * (1.f/1024.f) - m*m;
    float sc = g3[j] * rsqrtf(var + 1e-5f);
    float v = h3[(size_t)n*256 + j] * sc + (b3[j] - m*sc);
    a[i] = fmaxf(v, 0.f);
  }
  float alpha = absum[3] * (1.f/2560.f);
  #pragma unroll
  for (int k = 0; k < 10; ++k){
    float p = 0.f;
    #pragma unroll
    for (int i = 0; i < 4; ++i) p += a[i] * qwfc2[k*256 + lane + 64*i];
    #pragma unroll
    for (int off = 32; off > 0; off >>= 1) p += __shfl_down(p, off);
    if (lane == 0) out[n*10 + k] = p * alpha;
  }
}

extern "C" void kernel_launch(void* const* d_in, const int* in_sizes, int n_in,
                              void* d_out, int out_size, void* d_ws, size_t ws_size,
                              hipStream_t stream){
  (void)in_sizes; (void)n_in; (void)out_size; (void)ws_size;
  const float* x    = (const float*)d_in[0];
  const float* w1   = (const float*)d_in[1];
  const float* g1   = (const float*)d_in[2];
  const float* b1   = (const float*)d_in[3];
  const float* w2   = (const float*)d_in[4];
  const float* g2   = (const float*)d_in[5];
  const float* b2   = (const float*)d_in[6];
  const float* wfc1 = (const float*)d_in[7];
  const float* g3   = (const float*)d_in[8];
  const float* b3   = (const float*)d_in[9];
  const float* wfc2 = (const float*)d_in[10];
  float* out = (float*)d_out;

  float* wsf = (float*)d_ws;
  char*  wsb = (char*)d_ws;
  float* absum = wsf;
  float* s1 = wsf + 16;   float* q1 = wsf + 80;
  float* s2 = wsf + 144;  float* q2 = wsf + 272;
  float* s3 = wsf + 1024; float* q3 = wsf + 1280;
  float* partials = wsf + 2048;                      // 4x256 fp32 (zeroed)
  u16*   qw1b  = (u16*)(wsf + 4096);                 // 2048 u16 conv1 B-frags
  u16*   qw2b  = (u16*)(wsb + (64u << 10));          // 144 KB bf16 B-frags
  float* qwfc2 = (float*)(wsb + (256u << 10));       // 10 KB fp32
  float* h3    = (float*)(wsb + (1ull << 20));       // 1 MB fp32 [1024][256]
  u16*   qfc1b = (u16*)(wsb + (2ull << 20));         // 4 MB bf16 B-frags
  u16*   p1t   = (u16*)(wsb + (8ull << 20) + 4096);  // 32 MB bf16 [1024][256][64]
  u16*   p2    = (u16*)(wsb + (112ull << 20));       // 16 MB bf16 [1024][64][128] pooled raw -> bn2 in place
  float* h3p   = (float*)(wsb + (128ull << 20));     // 16 MB fp32 [16][1024][256]

  hipMemsetAsync(wsf, 0, 3072 * sizeof(float), stream);
  k_signgen_small<<<306, 256, 0, stream>>>(w1, w2, wfc2, qw1b, qw2b, qwfc2, partials);
  k_fc1gen<<<256, 256, 0, stream>>>(wfc1, qfc1b, partials);
  k_red4<<<1, 256, 0, stream>>>(partials, absum);
  k_conv1m<<<1024, 256, 0, stream>>>(x, qw1b, absum, p1t, s1, q1);
  k_conv2m<<<dim3(1024, 2), 256, 0, stream>>>(p1t, qw2b, absum, s1, q1, g1, b1, p2, s2, q2);
  k_bn2<<<4096, 256, 0, stream>>>(p2, s2, q2, g2, b2);
  k_fc1m<<<dim3(8, 2, 16), 256, 0, stream>>>(p2, qfc1b, absum, h3p);
  k_fin3f<<<dim3(8, 8), 256, 0, stream>>>(h3p, h3, s3, q3);
  k_fc2<<<1024, 64, 0, stream>>>(h3, qwfc2, absum, s3, q3, g3, b3, out);
}

// Round 14
// 234.618 us; speedup vs baseline: 2.4228x; 1.1117x over previous
//
#include <hip/hip_runtime.h>
#include <stdint.h>

typedef unsigned short u16;
typedef unsigned int u32;
typedef __attribute__((ext_vector_type(8))) short s8v;   // 8 bf16 = 4 VGPR (MFMA A/B frag)
typedef __attribute__((ext_vector_type(4))) float f4v;   // MFMA C/D frag
typedef __attribute__((ext_vector_type(8))) u16 u16x8;

// ---------- bf16 helpers ----------
__device__ __forceinline__ float bf2f(u16 u){
  union { u32 i; float f; } v; v.i = ((u32)u) << 16; return v.f;
}
__device__ __forceinline__ u16 f2bf(float f){
  union { float f; u32 i; } v; v.f = f;
  u32 i = v.i;
  return (u16)((i + 0x7fffu + ((i >> 16) & 1u)) >> 16); // RNE
}
__device__ __forceinline__ float sgnf(float w){
  return (w > 0.f) ? 1.f : ((w < 0.f) ? -1.f : 0.f);
}
__device__ __forceinline__ u16 sgn_bf(float w){
  return (w > 0.f) ? (u16)0x3F80 : ((w < 0.f) ? (u16)0xBF80 : (u16)0);
}

// ---------- sign-gen for the SMALL weights (w2, w1, wfc2) + absum partials ----------
__global__ __launch_bounds__(256) void k_signgen_small(const float* __restrict__ w1, const float* __restrict__ w2,
                                                       const float* __restrict__ wfc2,
                                                       u16* __restrict__ qw1b, u16* __restrict__ qw2b,
                                                       float* __restrict__ qwfc2, float* __restrict__ partials){
  int i = blockIdx.x * 256 + threadIdx.x;
  float av = 0.f; int slot;
  if (i < 73728){
    int j = i & 7, lane = (i >> 3) & 63, fid = i >> 9;    // 0..143
    int s = fid >> 4, ks = (fid >> 3) & 1, nt = fid & 7;
    int co = (lane & 15)*8 + nt;
    int c = ks*32 + (lane >> 4)*8 + j;
    float wv = w2[((size_t)co*64 + c)*9 + s];
    qw2b[i] = sgn_bf(wv);
    av = fabsf(wv); slot = 1;
  } else if (i < 73728 + 2048){
    int i3 = i - 73728;
    int j = i3 & 7, lane = (i3 >> 3) & 63, nt = i3 >> 9;  // 0..3
    int co = nt*16 + (lane & 15);
    int k = (lane >> 4)*8 + j;
    if (k < 27){
      float wv = w1[co*27 + k];
      qw1b[i3] = sgn_bf(wv);
      av = fabsf(wv);
    } else qw1b[i3] = (u16)0;
    slot = 0;
  } else {
    int i4 = i - (73728 + 2048);
    float wv = wfc2[i4];
    qwfc2[i4] = sgnf(wv);
    av = fabsf(wv); slot = 3;
  }
  #pragma unroll
  for (int off = 32; off > 0; off >>= 1) av += __shfl_xor(av, off);
  if ((threadIdx.x & 63) == 0) atomicAdd(partials + slot*256 + (blockIdx.x & 255), av);
}

// ---------- wfc1 sign + k-permute via LDS transpose (coalesced; the direct gather cost
// ~128 MB effective traffic at 256B stride) ----------
__global__ __launch_bounds__(256) void k_fc1gen(const float* __restrict__ wfc1, u16* __restrict__ qfc1b,
                                                float* __restrict__ partials){
  __shared__ u16 tile[128*72];   // [c][px], row pad 64->72 (18 KB)
  int co = blockIdx.x, t = threadIdx.x;
  const float4* src = (const float4*)(wfc1 + (size_t)co*8192);
  float av = 0.f;
  #pragma unroll
  for (int p = 0; p < 8; ++p){
    int k4 = t + p*256;              // float4 index; k_src = k4*4
    float4 v = src[k4];
    int c = k4 >> 4, px = (k4 & 15)*4;   // k_src>>6, k_src&63
    u16* d = tile + c*72 + px;
    d[0] = sgn_bf(v.x); d[1] = sgn_bf(v.y); d[2] = sgn_bf(v.z); d[3] = sgn_bf(v.w);
    av += fabsf(v.x) + fabsf(v.y) + fabsf(v.z) + fabsf(v.w);
  }
  #pragma unroll
  for (int off = 32; off > 0; off >>= 1) av += __shfl_xor(av, off);
  if ((t & 63) == 0) atomicAdd(partials + 2*256 + (co & 255), av);
  __syncthreads();
  int co4 = co >> 4, co15 = co & 15;
  #pragma unroll
  for (int p = 0; p < 4; ++p){
    int m = t + p*256;               // chunk id = px*16 + jj
    int px = m >> 4, jj = m & 15;
    int kstep = px*4 + (jj >> 2), l16 = jj & 3;
    u16x8 o;
    #pragma unroll
    for (int u = 0; u < 8; ++u) o[u] = tile[(jj*8 + u)*72 + px];
    *(u16x8*)(qfc1b + ((size_t)(kstep*16 + co4)*512 + (l16*16 + co15)*8)) = o;
  }
}

// ---------- reduce 4x256 partials -> absum[4] ----------
__global__ void k_red4(const float* __restrict__ partials, float* __restrict__ absum){
  int t = threadIdx.x, w = t >> 6, lane = t & 63;
  const float* p = partials + w*256;
  float s = p[lane] + p[lane + 64] + p[lane + 128] + p[lane + 192];
  #pragma unroll
  for (int off = 32; off > 0; off >>= 1) s += __shfl_xor(s, off);
  if (lane == 0) absum[w] = s;
}

// ---------- conv1 via MFMA: im2col in LDS + fused BN1 stats + in-lane 2x2 pool ----------
__global__ __launch_bounds__(256) void k_conv1m(const float* __restrict__ x, const u16* __restrict__ qw1b,
                                                const float* __restrict__ absum, u16* __restrict__ p1raw,
                                                float* __restrict__ gs, float* __restrict__ gq){
  __shared__ float xs[3*34*36];              // fp32 halo image, data y=1..32, x=2..33
  __shared__ __align__(16) u16 acol[256*40]; // im2col chunk: 256 rows x 40 u16 (32 used)
  __shared__ float ls1[64], ls2[64];
  int n = blockIdx.x, t = threadIdx.x;
  if (t < 64){ ls1[t] = 0.f; ls2[t] = 0.f; }
  for (int i = t; i < 3672; i += 256) xs[i] = 0.f;
  __syncthreads();
  const float4* xg = (const float4*)(x + (size_t)n * 3072);
  for (int i = t; i < 768; i += 256){
    float4 v = xg[i];
    int ci = i >> 8, rem = i & 255, y = rem >> 3, xq = (rem & 7) * 4;
    int base = ci*1224 + (y+1)*36 + 2 + xq;
    xs[base+0] = v.x; xs[base+1] = v.y; xs[base+2] = v.z; xs[base+3] = v.w;
  }
  int w = t >> 6, lane = t & 63, l15 = lane & 15, q = lane >> 4;
  const s8v* bp = (const s8v*)qw1b;
  s8v bf[4];
  #pragma unroll
  for (int nt = 0; nt < 4; ++nt) bf[nt] = bp[nt*64 + lane];
  float alpha = absum[0] * (1.f/1728.f);
  u16* p1img = p1raw + (size_t)n * 16384;
  float s1v[4], s2v[4];
  #pragma unroll
  for (int nt = 0; nt < 4; ++nt){ s1v[nt] = 0.f; s2v[nt] = 0.f; }
  for (int chunk = 0; chunk < 4; ++chunk){
    __syncthreads();
    {
      int mg = chunk*256 + t;
      int g = mg >> 2, s = mg & 3;
      int iy = 2*(g >> 4) + (s >> 1), ix = 2*(g & 15) + (s & 1);
      const float* xb = xs + iy*36 + ix + 1;
      u32 pk2[16];
      #pragma unroll
      for (int kk = 0; kk < 16; ++kk){
        int k0 = 2*kk, k1 = 2*kk + 1;
        u32 lo = (k0 < 27) ? (u32)f2bf(xb[(k0/9)*1224 + ((k0%9)/3)*36 + (k0%3)]) : 0u;
        u32 hi = (k1 < 27) ? (u32)f2bf(xb[(k1/9)*1224 + ((k1%9)/3)*36 + (k1%3)]) : 0u;
        pk2[kk] = lo | (hi << 16);
      }
      u32* ar = (u32*)(acol + t*40);
      #pragma unroll
      for (int v = 0; v < 4; ++v)
        *(uint4*)(ar + v*4) = make_uint4(pk2[v*4], pk2[v*4+1], pk2[v*4+2], pk2[v*4+3]);
    }
    __syncthreads();
    #pragma unroll
    for (int i = 0; i < 4; ++i){
      int tl = w*4 + i;
      s8v av = *(const s8v*)(acol + (tl*16 + l15)*40 + q*8);
      int g = chunk*64 + tl*4 + q;
      u16* drow = p1img + g*64 + l15;
      #pragma unroll
      for (int nt = 0; nt < 4; ++nt){
        f4v c = (f4v)(0.0f);
        c = __builtin_amdgcn_mfma_f32_16x16x32_bf16(av, bf[nt], c, 0, 0, 0);
        s1v[nt] += c[0] + c[1] + c[2] + c[3];
        s2v[nt] += c[0]*c[0] + c[1]*c[1] + c[2]*c[2] + c[3]*c[3];
        float pm = fmaxf(fmaxf(c[0], c[1]), fmaxf(c[2], c[3]));
        drow[nt*16] = f2bf(pm * alpha);
      }
    }
  }
  #pragma unroll
  for (int nt = 0; nt < 4; ++nt){
    s1v[nt] += __shfl_xor(s1v[nt], 16); s1v[nt] += __shfl_xor(s1v[nt], 32);
    s2v[nt] += __shfl_xor(s2v[nt], 16); s2v[nt] += __shfl_xor(s2v[nt], 32);
  }
  if (q == 0){
    #pragma unroll
    for (int nt = 0; nt < 4; ++nt){
      atomicAdd(&ls1[nt*16 + l15], s1v[nt]);
      atomicAdd(&ls2[nt*16 + l15], s2v[nt]);
    }
  }
  __syncthreads();
  if (t < 64){
    atomicAdd(gs + t, ls1[t] * alpha);
    atomicAdd(gq + t, ls2[t] * alpha * alpha);
  }
}

// ---------- conv2 via MFMA: EXACT R10 structure (proven 63.5 us / 96 VGPR / no spill).
// R11 nt-split (acc[16][2]) -> 800 MB spill; R13 co-half split -> allocator pinned 56 VGPR
// + 2x staging VALU + 2x write amp (87 us). acc[4][8]+bf[8] is the only register shape the
// allocator handles cleanly here. BN1 inline staging; in-register 2x2 pool; stats overlay img.
__global__ __launch_bounds__(256, 2) void k_conv2m(const u16* __restrict__ p1raw, const u16* __restrict__ qw2b,
                                                   const float* __restrict__ absum,
                                                   const float* __restrict__ s1, const float* __restrict__ q1,
                                                   const float* __restrict__ g1, const float* __restrict__ b1,
                                                   u16* __restrict__ p2raw,
                                                   float* __restrict__ gs, float* __restrict__ gq){
  __shared__ __align__(16) u16 img[16384];   // 32 KB exactly; reused for stats after compute
  int n = blockIdx.x, t = threadIdx.x;
  int c0 = (t & 7) * 8;
  float scv[8], biv[8];
  #pragma unroll
  for (int j = 0; j < 8; ++j){
    float m = s1[c0+j] * (1.f/1048576.f);
    float var = q1[c0+j] * (1.f/1048576.f) - m*m;
    float sc = g1[c0+j] * rsqrtf(var + 1e-5f);
    scv[j] = sc; biv[j] = b1[c0+j] - m*sc;
  }
  const u16* src = p1raw + (size_t)n * 16384;
  #pragma unroll
  for (int i = 0; i < 8; ++i){
    int id = i*256 + t;            // = px*8 + unit, unit == t&7
    int px = id >> 3, unit = id & 7;
    int su = unit ^ (px & 7);
    u16x8 v = *(const u16x8*)(src + id*8);
    u16x8 o;
    #pragma unroll
    for (int j = 0; j < 8; ++j)
      o[j] = f2bf(fmaxf(bf2f(v[j]) * scv[j] + biv[j], 0.f));
    *(u16x8*)(img + px*64 + su*8) = o;
  }
  __syncthreads();
  int w = t >> 6, lane = t & 63, l15 = lane & 15, q = lane >> 4;
  const s8v* bp = (const s8v*)qw2b;
  f4v acc[4][8];
  #pragma unroll
  for (int a = 0; a < 4; ++a)
    #pragma unroll
    for (int b = 0; b < 8; ++b) acc[a][b] = (f4v)(0.0f);
  #pragma unroll
  for (int dy = 0; dy < 3; ++dy){
    #pragma unroll
    for (int dx = 0; dx < 3; ++dx){
      int s = dy*3 + dx;
      int xv = l15 + dx - 1;
      bool vx = (xv >= 0) && (xv < 16);
      int xc = min(max(xv, 0), 15);
      #pragma unroll
      for (int ks = 0; ks < 2; ++ks){
        s8v bf[8];
        #pragma unroll
        for (int nt = 0; nt < 8; ++nt) bf[nt] = bp[((s*2 + ks)*8 + nt)*64 + lane];
        #pragma unroll
        for (int mt = 0; mt < 4; ++mt){
          int yv = w*4 + mt + dy - 1;
          if (yv < 0 || yv > 15) continue;
          int px = yv*16 + xc;
          int su = (ks*4 + q) ^ (px & 7);
          s8v av = *(const s8v*)(img + px*64 + su*8);
          if (!vx) av = (s8v)(short)0;
          #pragma unroll
          for (int nt = 0; nt < 8; ++nt)
            acc[mt][nt] = __builtin_amdgcn_mfma_f32_16x16x32_bf16(av, bf[nt], acc[mt][nt], 0, 0, 0);
        }
      }
    }
  }
  float alpha = absum[1] * (1.f/73728.f);
  float s1v[8], s2v[8];
  #pragma unroll
  for (int nt = 0; nt < 8; ++nt){ s1v[nt] = 0.f; s2v[nt] = 0.f; }
  // in-register 2x2 pool: this wave's rows w*4..w*4+3 pair into pooled rows w*2, w*2+1
  #pragma unroll
  for (int mp = 0; mp < 2; ++mp){
    #pragma unroll
    for (int rp = 0; rp < 2; ++rp){
      u16x8 pk;
      #pragma unroll
      for (int nt = 0; nt < 8; ++nt){
        float v0 = acc[2*mp][nt][2*rp]     * alpha;
        float v1 = acc[2*mp][nt][2*rp+1]   * alpha;
        float v2 = acc[2*mp+1][nt][2*rp]   * alpha;
        float v3 = acc[2*mp+1][nt][2*rp+1] * alpha;
        s1v[nt] += v0 + v1 + v2 + v3;
        s2v[nt] += v0*v0 + v1*v1 + v2*v2 + v3*v3;
        pk[nt] = f2bf(fmaxf(fmaxf(v0, v1), fmaxf(v2, v3)));
      }
      int opx = (w*2 + mp)*8 + (q*2 + rp);  // pooled 8x8 index
      *(u16x8*)(p2raw + ((size_t)n*64 + opx)*128 + l15*8) = pk;
    }
  }
  #pragma unroll
  for (int nt = 0; nt < 8; ++nt){
    s1v[nt] += __shfl_xor(s1v[nt], 16); s1v[nt] += __shfl_xor(s1v[nt], 32);
    s2v[nt] += __shfl_xor(s2v[nt], 16); s2v[nt] += __shfl_xor(s2v[nt], 32);
  }
  __syncthreads();                 // all waves done reading img -> reuse as stats LDS
  float* ls = (float*)img;         // ls[0..127]=sum, ls[128..255]=sumsq
  if (t < 256) ls[t] = 0.f;
  __syncthreads();
  if (q == 0){
    #pragma unroll
    for (int nt = 0; nt < 8; ++nt){
      atomicAdd(&ls[l15*8 + nt], s1v[nt]);
      atomicAdd(&ls[128 + l15*8 + nt], s2v[nt]);
    }
  }
  __syncthreads();
  if (t < 128){ atomicAdd(gs + t, ls[t]); atomicAdd(gq + t, ls[128 + t]); }
}

// ---------- BN2 affine + ReLU in-place on p2[1024][64px][128c] (params inline) ----------
__global__ __launch_bounds__(256) void k_bn2(u16* __restrict__ p2,
                                             const float* __restrict__ s2, const float* __restrict__ q2,
                                             const float* __restrict__ g2, const float* __restrict__ b2){
  size_t i = (size_t)blockIdx.x * 256 + threadIdx.x;   // unit of 8 u16
  int c0 = ((int)(i & 15)) * 8;
  float scv[8], biv[8];
  #pragma unroll
  for (int j = 0; j < 8; ++j){
    float m = s2[c0+j] * (1.f/262144.f);
    float var = q2[c0+j] * (1.f/262144.f) - m*m;
    float sc = g2[c0+j] * rsqrtf(var + 1e-5f);
    scv[j] = sc; biv[j] = b2[c0+j] - m*sc;
  }
  u16x8 v = *(u16x8*)(p2 + i*8);
  u16x8 o;
  #pragma unroll
  for (int j = 0; j < 8; ++j)
    o[j] = f2bf(fmaxf(bf2f(v[j]) * scv[j] + biv[j], 0.f));
  *(u16x8*)(p2 + i*8) = o;
}

// ---------- fc1 via MFMA, k-split 16: p2[1024][8192] x signs -> h3p[16][1024][256] ----------
__global__ __launch_bounds__(256) void k_fc1m(const u16* __restrict__ p2, const u16* __restrict__ qfc1b,
                                              const float* __restrict__ absum, float* __restrict__ h3p){
  int t = threadIdx.x;
  int bm = blockIdx.x, bn = blockIdx.y, kb = blockIdx.z;
  int w = t >> 6, lane = t & 63, l15 = lane & 15, q = lane >> 4;
  int rowbase = bm*128 + (w >> 1)*64;
  int ntb = bn*8 + (w & 1)*4;
  const s8v* bp = (const s8v*)qfc1b;
  f4v acc[4][4];
  #pragma unroll
  for (int a = 0; a < 4; ++a)
    #pragma unroll
    for (int b = 0; b < 4; ++b) acc[a][b] = (f4v)(0.0f);
  #pragma unroll 2
  for (int ks = 0; ks < 16; ++ks){
    int kst = kb*16 + ks;
    s8v bf[4], af[4];
    #pragma unroll
    for (int nt = 0; nt < 4; ++nt) bf[nt] = bp[(kst*16 + ntb + nt)*64 + lane];
    #pragma unroll
    for (int mt = 0; mt < 4; ++mt)
      af[mt] = *(const s8v*)(p2 + (size_t)(rowbase + mt*16 + l15)*8192 + kst*32 + q*8);
    #pragma unroll
    for (int mt = 0; mt < 4; ++mt)
      #pragma unroll
      for (int nt = 0; nt < 4; ++nt)
        acc[mt][nt] = __builtin_amdgcn_mfma_f32_16x16x32_bf16(af[mt], bf[nt], acc[mt][nt], 0, 0, 0);
  }
  float alpha = absum[2] * (1.f/2097152.f);
  float* dst = h3p + (size_t)kb * 262144;
  #pragma unroll
  for (int mt = 0; mt < 4; ++mt)
    #pragma unroll
    for (int nt = 0; nt < 4; ++nt){
      int col = (ntb + nt)*16 + l15;
      #pragma unroll
      for (int r = 0; r < 4; ++r)
        dst[(size_t)(rowbase + mt*16 + q*4 + r)*256 + col] = acc[mt][nt][r] * alpha;
    }
}

// ---------- reduce k-split slabs + BN3 stats + materialize h3 ----------
__global__ __launch_bounds__(256) void k_fin3f(const float* __restrict__ h3p, float* __restrict__ h3,
                                               float* __restrict__ s3, float* __restrict__ q3){
  int jb = blockIdx.x, ns = blockIdx.y, t = threadIdx.x;
  int jj = t & 31, nn = t >> 5;
  int j = jb*32 + jj;
  float s1 = 0.f, s2 = 0.f;
  for (int i = nn; i < 128; i += 8){
    int n = i*8 + ns;
    float v = 0.f;
    #pragma unroll 8
    for (int kb = 0; kb < 16; ++kb) v += h3p[(size_t)kb*262144 + n*256 + j];
    h3[n*256 + j] = v;
    s1 += v; s2 += v*v;
  }
  __shared__ float l1[256], l2[256];
  l1[t] = s1; l2[t] = s2;
  __syncthreads();
  if (t < 32){
    float a = 0.f, b = 0.f;
    #pragma unroll
    for (int k = 0; k < 8; ++k){ a += l1[t+32*k]; b += l2[t+32*k]; }
    atomicAdd(s3 + jb*32 + t, a); atomicAdd(q3 + jb*32 + t, b);
  }
}

// ---------- fc2: relu(bn3(h3)) @ sign(wfc2)^T -> out[1024,10] fp32 (BN3 params inline) ----------
__global__ __launch_bounds__(64) void k_fc2(const float* __restrict__ h3, const float* __restrict__ qwfc2,
                                            const float* __restrict__ absum,
                                            const float* __restrict__ s3, const float* __restrict__ q3,
                                            const float* __restrict__ g3, const float* __restrict__ b3,
                                            float* __restrict__ out){
  int n = blockIdx.x, lane = threadIdx.x;
  float a[4];
  #pragma unroll
  for (int i = 0; i < 4; ++i){
    int j = lane + 64*i;
    float m = s3[j] * (1.f/1024.f);
    float var = q3[j] * (1.f/1024.f) - m*m;
    float sc = g3[j] * rsqrtf(var + 1e-5f);
    float v = h3[(size_t)n*256 + j] * sc + (b3[j] - m*sc);
    a[i] = fmaxf(v, 0.f);
  }
  float alpha = absum[3] * (1.f/2560.f);
  #pragma unroll
  for (int k = 0; k < 10; ++k){
    float p = 0.f;
    #pragma unroll
    for (int i = 0; i < 4; ++i) p += a[i] * qwfc2[k*256 + lane + 64*i];
    #pragma unroll
    for (int off = 32; off > 0; off >>= 1) p += __shfl_down(p, off);
    if (lane == 0) out[n*10 + k] = p * alpha;
  }
}

extern "C" void kernel_launch(void* const* d_in, const int* in_sizes, int n_in,
                              void* d_out, int out_size, void* d_ws, size_t ws_size,
                              hipStream_t stream){
  (void)in_sizes; (void)n_in; (void)out_size; (void)ws_size;
  const float* x    = (const float*)d_in[0];
  const float* w1   = (const float*)d_in[1];
  const float* g1   = (const float*)d_in[2];
  const float* b1   = (const float*)d_in[3];
  const float* w2   = (const float*)d_in[4];
  const float* g2   = (const float*)d_in[5];
  const float* b2   = (const float*)d_in[6];
  const float* wfc1 = (const float*)d_in[7];
  const float* g3   = (const float*)d_in[8];
  const float* b3   = (const float*)d_in[9];
  const float* wfc2 = (const float*)d_in[10];
  float* out = (float*)d_out;

  float* wsf = (float*)d_ws;
  char*  wsb = (char*)d_ws;
  float* absum = wsf;
  float* s1 = wsf + 16;   float* q1 = wsf + 80;
  float* s2 = wsf + 144;  float* q2 = wsf + 272;
  float* s3 = wsf + 1024; float* q3 = wsf + 1280;
  float* partials = wsf + 2048;                      // 4x256 fp32 (zeroed)
  u16*   qw1b  = (u16*)(wsf + 4096);                 // 2048 u16 conv1 B-frags
  u16*   qw2b  = (u16*)(wsb + (64u << 10));          // 144 KB bf16 B-frags
  float* qwfc2 = (float*)(wsb + (256u << 10));       // 10 KB fp32
  float* h3    = (float*)(wsb + (1ull << 20));       // 1 MB fp32 [1024][256]
  u16*   qfc1b = (u16*)(wsb + (2ull << 20));         // 4 MB bf16 B-frags
  u16*   p1t   = (u16*)(wsb + (8ull << 20) + 4096);  // 32 MB bf16 [1024][256][64]
  u16*   p2    = (u16*)(wsb + (112ull << 20));       // 16 MB bf16 [1024][64][128] pooled raw -> bn2 in place
  float* h3p   = (float*)(wsb + (128ull << 20));     // 16 MB fp32 [16][1024][256]

  hipMemsetAsync(wsf, 0, 3072 * sizeof(float), stream);
  k_signgen_small<<<306, 256, 0, stream>>>(w1, w2, wfc2, qw1b, qw2b, qwfc2, partials);
  k_fc1gen<<<256, 256, 0, stream>>>(wfc1, qfc1b, partials);
  k_red4<<<1, 256, 0, stream>>>(partials, absum);
  k_conv1m<<<1024, 256, 0, stream>>>(x, qw1b, absum, p1t, s1, q1);
  k_conv2m<<<1024, 256, 0, stream>>>(p1t, qw2b, absum, s1, q1, g1, b1, p2, s2, q2);
  k_bn2<<<4096, 256, 0, stream>>>(p2, s2, q2, g2, b2);
  k_fc1m<<<dim3(8, 2, 16), 256, 0, stream>>>(p2, qfc1b, absum, h3p);
  k_fin3f<<<dim3(8, 8), 256, 0, stream>>>(h3p, h3, s3, q3);
  k_fc2<<<1024, 64, 0, stream>>>(h3, qwfc2, absum, s3, q3, g3, b3, out);
}